// Round 5
// baseline (313.315 us; speedup 1.0000x reference)
//
#include <hip/hip_runtime.h>
#include <hip/hip_bf16.h>

typedef unsigned short u16;
typedef unsigned int u32;
typedef float f32x4 __attribute__((ext_vector_type(4)));
typedef u16 u16x4 __attribute__((ext_vector_type(4)));
typedef u16 u16x8 __attribute__((ext_vector_type(8)));
typedef __bf16 bf16x8 __attribute__((ext_vector_type(8)));

#define OUT_DIM 4096
#define IN_DIM  4096
#define M_DIM   8192   // 4 * 2048

__device__ __forceinline__ u16 f2bf(float f) {
  u32 u = __builtin_bit_cast(u32, f);
  return (u16)((u + 0x7FFFu + ((u >> 16) & 1u)) >> 16);
}

// ---------------------------------------------------------------------------
// W build: codebook gather + sign unpack + 2-level inverse Haar + scale -> bf16
// ---------------------------------------------------------------------------
__global__ __launch_bounds__(256) void build_w_kernel(
    const float* __restrict__ codebook, const float* __restrict__ scales,
    const int* __restrict__ indices, const int* __restrict__ signs,
    u16* __restrict__ W) {
  __shared__ float c[IN_DIM];
  const int o   = blockIdx.x;
  const int tid = threadIdx.x;
  for (int g = tid; g < IN_DIM / 8; g += 256) {
    const int idx = indices[o * (IN_DIM / 8) + g];
    const int sp  = signs[o * (IN_DIM / 8) + g];
    f32x4 c0 = *(const f32x4*)&codebook[idx * 8];
    f32x4 c1 = *(const f32x4*)&codebook[idx * 8 + 4];
    float v[8] = {c0[0], c0[1], c0[2], c0[3], c1[0], c1[1], c1[2], c1[3]};
#pragma unroll
    for (int j = 0; j < 8; ++j)
      c[g * 8 + j] = ((sp >> j) & 1) ? v[j] : -v[j];
  }
  __syncthreads();
  const float scale = scales[o];
  const float S = 0.70710678118654752440f;
  for (int t = tid; t < IN_DIM / 4; t += 256) {
    float a   = c[t];
    float d1  = c[IN_DIM / 4 + t];
    float d2a = c[IN_DIM / 2 + 2 * t];
    float d2b = c[IN_DIM / 2 + 2 * t + 1];
    float e  = (a + d1) * S;
    float od = (a - d1) * S;
    u16x4 w;
    w[0] = f2bf((e  + d2a) * S * scale);
    w[1] = f2bf((e  - d2a) * S * scale);
    w[2] = f2bf((od + d2b) * S * scale);
    w[3] = f2bf((od - d2b) * S * scale);
    *(u16x4*)&W[(size_t)o * IN_DIM + 4 * t] = w;
  }
}

// ---------------------------------------------------------------------------
// X f32 -> bf16
// ---------------------------------------------------------------------------
__global__ __launch_bounds__(256) void cvt_x_kernel(
    const float* __restrict__ X, u16* __restrict__ Xb) {
  const int stride = gridDim.x * blockDim.x;
  const int n8 = (M_DIM * IN_DIM) / 8;
  for (int i = blockIdx.x * blockDim.x + threadIdx.x; i < n8; i += stride) {
    f32x4 a = *(const f32x4*)&X[(size_t)i * 8];
    f32x4 b = *(const f32x4*)&X[(size_t)i * 8 + 4];
    u16x8 r;
    r[0] = f2bf(a[0]); r[1] = f2bf(a[1]); r[2] = f2bf(a[2]); r[3] = f2bf(a[3]);
    r[4] = f2bf(b[0]); r[5] = f2bf(b[1]); r[6] = f2bf(b[2]); r[7] = f2bf(b[3]);
    *(u16x8*)&Xb[(size_t)i * 8] = r;
  }
}

// ---------------------------------------------------------------------------
// GEMM: C[M][N] f32 = A[M][K](bf16) x B[N][K](bf16, B^T layout).
// R5: 256x128 tile, BK=32, 8 waves (4Mx2N, wave 64x64), ring-2 LDS (48 KiB
// static) + <=128 VGPR  =>  2 blocks/CU co-resident. 2-phase minimal loop
// (stage-next / JIT-read / 16 MFMA / vmcnt(0) / 1 barrier); the drain of one
// block overlaps the MFMA of the other (m114 mechanism).
// LDS buf (24 KiB): A 256x64B then B 128x64B. Involution swizzle
// o ^= ((o>>3)&0x30) on both the global source and the ds_read address.
// ---------------------------------------------------------------------------
__global__ __launch_bounds__(512, 4) void gemm_bt_kernel(
    const u16* __restrict__ A,   // [M_DIM][K]
    const u16* __restrict__ B,   // [OUT_DIM][K]
    float*     __restrict__ C) { // [M_DIM][OUT_DIM]
  constexpr int K    = IN_DIM;
  constexpr int NT   = K / 32;     // 128 K-tiles
  constexpr int BUFB = 24576;      // bytes per ring buffer (A 16K + B 8K)
  __shared__ __align__(16) char smem[2 * BUFB];

  const int tid  = threadIdx.x;
  const int wave = tid >> 6;
  const int lane = tid & 63;

  // XCD-aware bijective swizzle (grid = 1024, %8 == 0)
  const int swz = (blockIdx.x & 7) * 128 + (blockIdx.x >> 3);
  const int bm = (swz >> 5) * 256;   // 32 M-blocks
  const int bn = (swz & 31) * 128;   // 32 N-blocks

  const int wr  = (wave >> 1) * 64;   // wave M offset (4 M-waves)
  const int wc  = (wave & 1) * 64;    // wave N offset (2 N-waves)
  const int fr  = lane & 15;
  const int fkB = (lane >> 4) * 16;   // k-fragment byte offset in row

  // loop-invariant swizzled read offsets (involution: slot ^= (row>>1)&3)
  int offA[4], offB[4];
#pragma unroll
  for (int m = 0; m < 4; ++m) {
    int o = (wr + m * 16 + fr) * 64 + fkB;
    offA[m] = o ^ ((o >> 3) & 0x30);
  }
#pragma unroll
  for (int n = 0; n < 4; ++n) {
    int o = (wc + n * 16 + fr) * 64 + fkB;
    offB[n] = 16384 + (o ^ ((o >> 3) & 0x30));
  }

  // per-thread pre-swizzled global stage sources (inverse of read swizzle);
  // advanced by 32 elements (64 B) per K-tile.
  const u16* srcA0; const u16* srcA1; const u16* srcB0;
  {
    int d0 = tid * 16;
    int l0 = d0 ^ ((d0 >> 3) & 0x30);
    srcA0 = A + (size_t)(bm + (d0 >> 6)) * K + ((l0 & 63) >> 1);
    int d1 = 8192 + tid * 16;
    int l1 = d1 ^ ((d1 >> 3) & 0x30);
    srcA1 = A + (size_t)(bm + (d1 >> 6)) * K + ((l1 & 63) >> 1);
    srcB0 = B + (size_t)(bn + (d0 >> 6)) * K + ((l0 & 63) >> 1);
  }
  const int ldsW = wave * 1024;  // wave-uniform dest base (HW adds lane*16)

  auto stage = [&](int bufOff) {
    char* base = smem + bufOff + ldsW;
    __builtin_amdgcn_global_load_lds(
        (const __attribute__((address_space(1))) void*)srcA0,
        (__attribute__((address_space(3))) void*)(base), 16, 0, 0);
    __builtin_amdgcn_global_load_lds(
        (const __attribute__((address_space(1))) void*)srcA1,
        (__attribute__((address_space(3))) void*)(base + 8192), 16, 0, 0);
    __builtin_amdgcn_global_load_lds(
        (const __attribute__((address_space(1))) void*)srcB0,
        (__attribute__((address_space(3))) void*)(base + 16384), 16, 0, 0);
    srcA0 += 32; srcA1 += 32; srcB0 += 32;
  };

  f32x4 acc[4][4] = {};

  // prologue: stage tile 0 into buf0, drain, barrier
  stage(0);
  asm volatile("s_waitcnt vmcnt(0)" ::: "memory");
  __builtin_amdgcn_s_barrier();

  int curOff = 0;
  for (int t = 0; t < NT; ++t) {
    if (t + 1 < NT) stage(curOff ^ BUFB);   // async: lands before next gate
    const char* buf = smem + curOff;
    bf16x8 af[4], bfv[4];
#pragma unroll
    for (int n = 0; n < 4; ++n) bfv[n] = *(const bf16x8*)(buf + offB[n]);
#pragma unroll
    for (int m = 0; m < 4; ++m) af[m] = *(const bf16x8*)(buf + offA[m]);
    __builtin_amdgcn_s_setprio(1);
#pragma unroll
    for (int m = 0; m < 4; ++m)
#pragma unroll
      for (int n = 0; n < 4; ++n)
        acc[m][n] = __builtin_amdgcn_mfma_f32_16x16x32_bf16(af[m], bfv[n], acc[m][n], 0, 0, 0);
    __builtin_amdgcn_s_setprio(0);
    // gate: stage(t+1) retired + all waves' reads of buf done (lgkm drained
    // before their MFMAs) -> safe to read buf^1 / overwrite buf next iter.
    asm volatile("s_waitcnt vmcnt(0)" ::: "memory");
    __builtin_amdgcn_s_barrier();
    curOff ^= BUFB;
  }

  // epilogue: C/D layout col=lane&15, row=(lane>>4)*4+j (m89-verified)
#pragma unroll
  for (int m = 0; m < 4; ++m)
#pragma unroll
    for (int n = 0; n < 4; ++n) {
      const int col = bn + wc + n * 16 + fr;
#pragma unroll
      for (int j = 0; j < 4; ++j) {
        const int row = bm + wr + m * 16 + (lane >> 4) * 4 + j;
        C[(size_t)row * OUT_DIM + col] = acc[m][n][j];
      }
    }
}

// ---------------------------------------------------------------------------
extern "C" void kernel_launch(void* const* d_in, const int* in_sizes, int n_in,
                              void* d_out, int out_size, void* d_ws, size_t ws_size,
                              hipStream_t stream) {
  const float* x        = (const float*)d_in[0];
  const float* codebook = (const float*)d_in[1];
  const float* scales   = (const float*)d_in[2];
  const int*   indices  = (const int*)d_in[3];
  const int*   signs    = (const int*)d_in[4];
  float* out = (float*)d_out;

  u16* W  = (u16*)d_ws;
  u16* Xb = (u16*)d_ws + (size_t)OUT_DIM * IN_DIM;

  build_w_kernel<<<OUT_DIM, 256, 0, stream>>>(codebook, scales, indices, signs, W);
  cvt_x_kernel<<<2048, 256, 0, stream>>>(x, Xb);
  gemm_bt_kernel<<<(M_DIM / 256) * (OUT_DIM / 128), 512, 0, stream>>>(Xb, W, out);
}

// Round 6
// 285.967 us; speedup vs baseline: 1.0956x; 1.0956x over previous
//
#include <hip/hip_runtime.h>
#include <hip/hip_bf16.h>

typedef unsigned short u16;
typedef unsigned int u32;
typedef float f32x4 __attribute__((ext_vector_type(4)));
typedef u16 u16x4 __attribute__((ext_vector_type(4)));
typedef u16 u16x8 __attribute__((ext_vector_type(8)));
typedef __bf16 bf16x8 __attribute__((ext_vector_type(8)));

#define OUT_DIM 4096
#define IN_DIM  4096
#define M_DIM   8192   // 4 * 2048

__device__ __forceinline__ u16 f2bf(float f) {
  u32 u = __builtin_bit_cast(u32, f);
  return (u16)((u + 0x7FFFu + ((u >> 16) & 1u)) >> 16);
}

// ---------------------------------------------------------------------------
// W build: codebook gather + sign unpack + 2-level inverse Haar + scale -> bf16
// ---------------------------------------------------------------------------
__global__ __launch_bounds__(256) void build_w_kernel(
    const float* __restrict__ codebook, const float* __restrict__ scales,
    const int* __restrict__ indices, const int* __restrict__ signs,
    u16* __restrict__ W) {
  __shared__ float c[IN_DIM];
  const int o   = blockIdx.x;
  const int tid = threadIdx.x;
  for (int g = tid; g < IN_DIM / 8; g += 256) {
    const int idx = indices[o * (IN_DIM / 8) + g];
    const int sp  = signs[o * (IN_DIM / 8) + g];
    f32x4 c0 = *(const f32x4*)&codebook[idx * 8];
    f32x4 c1 = *(const f32x4*)&codebook[idx * 8 + 4];
    float v[8] = {c0[0], c0[1], c0[2], c0[3], c1[0], c1[1], c1[2], c1[3]};
#pragma unroll
    for (int j = 0; j < 8; ++j)
      c[g * 8 + j] = ((sp >> j) & 1) ? v[j] : -v[j];
  }
  __syncthreads();
  const float scale = scales[o];
  const float S = 0.70710678118654752440f;
  for (int t = tid; t < IN_DIM / 4; t += 256) {
    float a   = c[t];
    float d1  = c[IN_DIM / 4 + t];
    float d2a = c[IN_DIM / 2 + 2 * t];
    float d2b = c[IN_DIM / 2 + 2 * t + 1];
    float e  = (a + d1) * S;
    float od = (a - d1) * S;
    u16x4 w;
    w[0] = f2bf((e  + d2a) * S * scale);
    w[1] = f2bf((e  - d2a) * S * scale);
    w[2] = f2bf((od + d2b) * S * scale);
    w[3] = f2bf((od - d2b) * S * scale);
    *(u16x4*)&W[(size_t)o * IN_DIM + 4 * t] = w;
  }
}

// ---------------------------------------------------------------------------
// X f32 -> bf16
// ---------------------------------------------------------------------------
__global__ __launch_bounds__(256) void cvt_x_kernel(
    const float* __restrict__ X, u16* __restrict__ Xb) {
  const int stride = gridDim.x * blockDim.x;
  const int n8 = (M_DIM * IN_DIM) / 8;
  for (int i = blockIdx.x * blockDim.x + threadIdx.x; i < n8; i += stride) {
    f32x4 a = *(const f32x4*)&X[(size_t)i * 8];
    f32x4 b = *(const f32x4*)&X[(size_t)i * 8 + 4];
    u16x8 r;
    r[0] = f2bf(a[0]); r[1] = f2bf(a[1]); r[2] = f2bf(a[2]); r[3] = f2bf(a[3]);
    r[4] = f2bf(b[0]); r[5] = f2bf(b[1]); r[6] = f2bf(b[2]); r[7] = f2bf(b[3]);
    *(u16x8*)&Xb[(size_t)i * 8] = r;
  }
}

// ---------------------------------------------------------------------------
// GEMM: C[M][N] f32 = A[M][K](bf16) x B[N][K](bf16, B^T layout).
// R6: 8-phase template (m201 port). BM=BN=256, BK=64, 8 waves (2Mx4N),
// wave tile 128x64 (acc 8x4 frags). Ring-2 x 64 KiB LDS; each buffer = 4
// regions of 16 KiB by k-slab: {A.k0, B.k0, A.k1, B.k1}. Each region is
// consumed in exactly 2 consecutive phases and re-staged (2 tiles ahead)
// starting 1 phase after its last read. Gates: vmcnt(4) at phases 4 & 8
// only (counted, never 0 in steady state). Involution swizzle
// o ^= ((o>>3)&0x30) per 16 KiB region (zero conflicts, proven R2-R5).
// ---------------------------------------------------------------------------
__global__ __launch_bounds__(512, 1) void gemm_bt_kernel(
    const u16* __restrict__ A,   // [M_DIM][K]
    const u16* __restrict__ B,   // [OUT_DIM][K]
    float*     __restrict__ C) { // [M_DIM][OUT_DIM]
  constexpr int K   = IN_DIM;
  constexpr int NT  = K / 64;    // 64 K-tiles (BK=64)
  constexpr int NIT = NT / 2;    // 32 iterations (2 K-tiles each)
  extern __shared__ char smem[]; // 131072 B

  const int tid  = threadIdx.x;
  const int wave = tid >> 6;
  const int lane = tid & 63;

  // XCD-aware bijective swizzle (grid = 512, %8 == 0)
  const int swz = (blockIdx.x & 7) * 64 + (blockIdx.x >> 3);
  const int bm = (swz >> 4) * 256;   // 32 M-blocks
  const int bn = (swz & 15) * 256;   // 16 N-blocks

  const int wr  = (wave >> 2) * 128;  // 2 M-wave-groups
  const int wc  = (wave & 3) * 64;    // 4 N-wave-groups
  const int fr  = lane & 15;
  const int fkB = (lane >> 4) * 16;   // k-frag byte offset within 64B slab row

  // swizzled read offsets within a 16 KiB region (row stride 64 B)
  int offA[2][4], offB[4];
#pragma unroll
  for (int mq = 0; mq < 2; ++mq)
#pragma unroll
    for (int m = 0; m < 4; ++m) {
      int o = (wr + mq * 64 + m * 16 + fr) * 64 + fkB;
      offA[mq][m] = o ^ ((o >> 3) & 0x30);
    }
#pragma unroll
  for (int n = 0; n < 4; ++n) {
    int o = (wc + n * 16 + fr) * 64 + fkB;
    offB[n] = 16384 + (o ^ ((o >> 3) & 0x30));
  }

  // pre-swizzled global stage sources (inverse involution), rows split
  // load0: rows 0-127, load1: rows 128-255 of the 256-row region.
  const int d0 = tid * 16,        d1 = 8192 + tid * 16;
  const int l0 = d0 ^ ((d0 >> 3) & 0x30), l1 = d1 ^ ((d1 >> 3) & 0x30);
  const u16* srcA0 = A + (size_t)(bm + (d0 >> 6)) * K + ((l0 & 63) >> 1);
  const u16* srcA1 = A + (size_t)(bm + (d1 >> 6)) * K + ((l1 & 63) >> 1);
  const u16* srcB0 = B + (size_t)(bn + (d0 >> 6)) * K + ((l0 & 63) >> 1);
  const u16* srcB1 = B + (size_t)(bn + (d1 >> 6)) * K + ((l1 & 63) >> 1);
  const int ldsW = wave * 1024;  // wave-uniform dest base (HW adds lane*16)

#define GLD(SRC, DST)                                              \
  __builtin_amdgcn_global_load_lds(                                \
      (const __attribute__((address_space(1))) void*)(SRC),        \
      (__attribute__((address_space(3))) void*)(DST), 16, 0, 0)

  // stage one 16 KiB region-part: part 0 = A-slab, part 1 = B-slab
  auto stagePart = [&](int bufi, int ks, int part, int tile) {
    char* base = smem + bufi * 65536 + ks * 32768 + part * 16384 + ldsW;
    const u16* s0 = (part ? srcB0 : srcA0) + tile * 64 + ks * 32;
    const u16* s1 = (part ? srcB1 : srcA1) + tile * 64 + ks * 32;
    GLD(s0, base);
    GLD(s1, base + 8192);
  };

  f32x4 acc[8][4] = {};
  bf16x8 aq[4], bq[4];

  // prologue: T0.k0(A,B), T0.k1(A,B), T1.k0(A,B) = 12 loads; retire T0 fully
  stagePart(0, 0, 0, 0); stagePart(0, 0, 1, 0);
  stagePart(0, 1, 0, 0); stagePart(0, 1, 1, 0);
  stagePart(1, 0, 0, 1); stagePart(1, 0, 1, 1);
  asm volatile("s_waitcnt vmcnt(4)" ::: "memory");
  __builtin_amdgcn_s_barrier();

#define PHASE(BUFI, KS, MQ, READB, STAGE, GATE)                              \
  {                                                                          \
    const char* rb = smem + (BUFI) * 65536 + (KS) * 32768;                   \
    if (READB) {                                                             \
      _Pragma("unroll")                                                      \
      for (int n = 0; n < 4; ++n) bq[n] = *(const bf16x8*)(rb + offB[n]);    \
    }                                                                        \
    _Pragma("unroll")                                                        \
    for (int m = 0; m < 4; ++m) aq[m] = *(const bf16x8*)(rb + offA[MQ][m]);  \
    STAGE;                                                                   \
    __builtin_amdgcn_s_barrier();                                            \
    asm volatile("s_waitcnt lgkmcnt(0)" ::: "memory");                       \
    __builtin_amdgcn_s_setprio(1);                                           \
    _Pragma("unroll")                                                        \
    for (int m = 0; m < 4; ++m)                                              \
      _Pragma("unroll")                                                      \
      for (int n = 0; n < 4; ++n)                                            \
        acc[(MQ) * 4 + m][n] = __builtin_amdgcn_mfma_f32_16x16x32_bf16(      \
            aq[m], bq[n], acc[(MQ) * 4 + m][n], 0, 0, 0);                    \
    __builtin_amdgcn_s_setprio(0);                                           \
    GATE;                                                                    \
    __builtin_amdgcn_s_barrier();                                            \
  }

  for (int i = 0; i < NIT; ++i) {
    const int t0 = 2 * i;
    const bool more = (i < NIT - 1);
    // phases 1-4: consume buf0 (tile t0); phases 5-8: buf1 (tile t0+1)
    PHASE(0, 0, 0, 1, stagePart(1, 1, 0, t0 + 1), )
    PHASE(0, 0, 1, 0, stagePart(1, 1, 1, t0 + 1), )
    PHASE(0, 1, 0, 1, if (more) stagePart(0, 0, 0, t0 + 2), )
    PHASE(0, 1, 1, 0, if (more) stagePart(0, 0, 1, t0 + 2),
          if (more) { asm volatile("s_waitcnt vmcnt(4)" ::: "memory"); }
          else      { asm volatile("s_waitcnt vmcnt(0)" ::: "memory"); })
    PHASE(1, 0, 0, 1, if (more) stagePart(0, 1, 0, t0 + 2), )
    PHASE(1, 0, 1, 0, if (more) stagePart(0, 1, 1, t0 + 2), )
    PHASE(1, 1, 0, 1, if (more) stagePart(1, 0, 0, t0 + 3), )
    PHASE(1, 1, 1, 0, if (more) stagePart(1, 0, 1, t0 + 3),
          if (more) { asm volatile("s_waitcnt vmcnt(4)" ::: "memory"); }
          else      { asm volatile("s_waitcnt vmcnt(0)" ::: "memory"); })
  }
#undef PHASE
#undef GLD

  // epilogue: C/D layout col=lane&15, row=(lane>>4)*4+j (m89-verified)
#pragma unroll
  for (int h = 0; h < 8; ++h)
#pragma unroll
    for (int n = 0; n < 4; ++n) {
      const int col = bn + wc + n * 16 + fr;
#pragma unroll
      for (int j = 0; j < 4; ++j) {
        const int row = bm + wr + h * 16 + (lane >> 4) * 4 + j;
        C[(size_t)row * OUT_DIM + col] = acc[h][n][j];
      }
    }
}

// ---------------------------------------------------------------------------
extern "C" void kernel_launch(void* const* d_in, const int* in_sizes, int n_in,
                              void* d_out, int out_size, void* d_ws, size_t ws_size,
                              hipStream_t stream) {
  const float* x        = (const float*)d_in[0];
  const float* codebook = (const float*)d_in[1];
  const float* scales   = (const float*)d_in[2];
  const int*   indices  = (const int*)d_in[3];
  const int*   signs    = (const int*)d_in[4];
  float* out = (float*)d_out;

  u16* W  = (u16*)d_ws;
  u16* Xb = (u16*)d_ws + (size_t)OUT_DIM * IN_DIM;

  (void)hipFuncSetAttribute((const void*)gemm_bt_kernel,
                            hipFuncAttributeMaxDynamicSharedMemorySize, 131072);

  build_w_kernel<<<OUT_DIM, 256, 0, stream>>>(codebook, scales, indices, signs, W);
  cvt_x_kernel<<<2048, 256, 0, stream>>>(x, Xb);
  gemm_bt_kernel<<<(M_DIM / 256) * (OUT_DIM / 256), 512, 131072, stream>>>(Xb, W, out);
}